// Round 12
// baseline (464.357 us; speedup 1.0000x reference)
//
#include <hip/hip_runtime.h>
#include <math.h>

#define N_ROWS 16384
#define DMODEL 1024
#define DFF    4096

typedef _Float16 f16;
typedef __attribute__((ext_vector_type(4))) _Float16 f16x4;
typedef __attribute__((ext_vector_type(8))) _Float16 f16x8;
typedef __attribute__((ext_vector_type(4))) float f32x4;
typedef __attribute__((ext_vector_type(16))) float f32x16;

__device__ inline void async_ld16(const f16* g, f16* l) {
  __builtin_amdgcn_global_load_lds(
      (__attribute__((address_space(1))) void*)(g),
      (__attribute__((address_space(3))) void*)(l),
      16, 0, 0);
}

// tanh via hw v_exp_f32: ~5 VALU ops vs libm tanhf's branchy ~40.
__device__ inline float fast_tanh(float x) {
  float t = __expf(2.0f * x);
  return 1.0f - 2.0f / (t + 1.0f);
}

// Merged pre-pass: casts batch/W1/W2 f32->f16 AND zeroes the row-accumulator.
__global__ void cast_and_zero(const float* __restrict__ batch, f16* __restrict__ batch_h,
                              const float* __restrict__ W1, f16* __restrict__ W1_h,
                              const float* __restrict__ W2, f16* __restrict__ W2_h,
                              float* __restrict__ rowacc) {
  const size_t nb = (size_t)N_ROWS * DMODEL;
  const size_t nw = (size_t)DFF * DMODEL;
  size_t off = ((size_t)blockIdx.x * blockDim.x + threadIdx.x) * 8;
  const float* src; f16* dst; size_t o;
  if (off < nb) { src = batch; dst = batch_h; o = off; }
  else if (off < nb + nw) { src = W1; dst = W1_h; o = off - nb; }
  else if (off < nb + 2 * nw) { src = W2; dst = W2_h; o = off - nb - nw; }
  else {  // zero 8 floats of rowacc
    size_t z = off - nb - 2 * nw;
    float4 zz = {0.f, 0.f, 0.f, 0.f};
    ((float4*)(rowacc + z))[0] = zz;
    ((float4*)(rowacc + z))[1] = zz;
    return;
  }
  float4 v0 = ((const float4*)(src + o))[0];
  float4 v1 = ((const float4*)(src + o))[1];
  f16x8 h = { (f16)v0.x, (f16)v0.y, (f16)v0.z, (f16)v0.w,
              (f16)v1.x, (f16)v1.y, (f16)v1.z, (f16)v1.w };
  *(f16x8*)(dst + o) = h;
}

#define BARRIER() __builtin_amdgcn_s_barrier()
#define WAIT_VMCNT(n) asm volatile("s_waitcnt vmcnt(" #n ")")

// ---------------------------------------------------------------------------
// r11 post-mortem: FETCH 270->98.5MB with ZERO time change -> HBM volume was
// never the pacer. Surviving model: per-tile time = MFMA(2483cy) + LDS-read
// (2312cy) + LDS-DMA-write(772cy) behaving SERIALIZED across all structures.
// Suspect: register-file port contention (16x16x32 MFMA reads 8 operand VGPRs
// per ~19cy while ds_read_b128 writebacks land). This round's single change:
// 32x32x16 MFMA -> halves MFMA instr count & operand-port traffic per FLOP,
// MFMA floor 2483->~2160cy (ubench 2382 vs 2075 TF). LDS bytes unchanged.
//
// Frag maps (generalizing the m89-verified 16x16 pattern; C/D per m74/m101):
//   A/B: row = lane&31, k = (lane>>5)*8 + j  (f16x8 = b128 per frag)
//   C/D: col = lane&31, row = (reg&3) + 8*(reg>>2) + 4*(lane>>5)
// Bank check under the existing slot^=(row>>1)&3 swizzle: 64 lanes cover the
// 8 16B-granules x 8 lanes = 8 accesses/bank = wave64 minimum. Conflict-free.
//
// GEMM core otherwise = r6/r11: 2-phase counted-vmcnt, XCD band map
// (FETCH-validated r10/r11), both-sides staging swizzle (rule #21).
// FUSE=false: C = tanh(A@B^T + bias) (GEMM1).
// FUSE=true : rowacc[row] += sum_col tanh(..)*batchf (GEMM2+rowdot fused).
// ---------------------------------------------------------------------------
template <int K, bool FUSE>
__global__ __launch_bounds__(512, 2)
void gemm256_tanh(const f16* __restrict__ A, const f16* __restrict__ B,
                  const float* __restrict__ bias, f16* __restrict__ C, int Nc,
                  float* __restrict__ rowacc, const float* __restrict__ batchf) {
  extern __shared__ __align__(16) char smem[];
  f16* lds = (f16*)smem;

  const int tid  = threadIdx.x;
  const int lane = tid & 63;
  const int wave = tid >> 6;
  const int wm = (wave >> 2) * 128;
  const int wn = (wave & 3) * 64;
  const int l31  = lane & 31;
  const int half = lane >> 5;

  // XCD band mapping (r10/r11-validated: FETCH 270->98.5 MB)
  const int nbx = gridDim.x;
  const int lin = blockIdx.y * nbx + blockIdx.x;
  const int xcd = lin & 7;
  const int c   = lin >> 3;
  const int rband = nbx >> 3;
  const size_t row0 = (size_t)(xcd * rband + (c % rband)) * 256;
  const size_t col0 = (size_t)(c / rband) * 256;

  // Staging (unchanged): per unit (kk-half, 256x32 f16 = 16KB), thread covers
  // 16B slots s = l*512+tid; source chunk pre-swizzled: (s&3)^((s>>3)&3).
  const int schunk = (tid & 3) ^ ((tid >> 3) & 3);
  const f16* Asrc[2]; const f16* Bsrc[2];
  const int sdst0 = tid * 8;
  const int sdst1 = 4096 + tid * 8;
  Asrc[0] = A + (row0 + (tid >> 2)) * (size_t)K + schunk * 8;
  Asrc[1] = A + (row0 + 128 + (tid >> 2)) * (size_t)K + schunk * 8;
  Bsrc[0] = B + (col0 + (tid >> 2)) * (size_t)K + schunk * 8;
  Bsrc[1] = B + (col0 + 128 + (tid >> 2)) * (size_t)K + schunk * 8;

  // 32x32 fragment reads: row = tile_base + l31; 16B slot = ks*2+half, then
  // ^= (row>>1)&3 (same involution as the staging pre-swizzle).
  auto aoff = [&](int d, int kk, int mt, int ks) -> int {
    const int row = wm + mt * 32 + l31;
    const int slot = (ks * 2 + half) ^ ((row >> 1) & 3);
    return d * 32768 + kk * 8192 + row * 32 + slot * 8;
  };
  auto boff = [&](int d, int kk, int nt, int ks) -> int {
    const int row = wn + nt * 32 + l31;
    const int slot = (ks * 2 + half) ^ ((row >> 1) & 3);
    return d * 32768 + 16384 + kk * 8192 + row * 32 + slot * 8;
  };
  auto stage_unit = [&](int j, int db, int kb) {
    const int o = j & 1, kk = j >> 1;
    const int dbase = db * 32768 + o * 16384 + kk * 8192;
    async_ld16((o ? Bsrc[0] : Asrc[0]) + kb + kk * 32, lds + dbase + sdst0);
    async_ld16((o ? Bsrc[1] : Asrc[1]) + kb + kk * 32, lds + dbase + sdst1);
  };

  f32x16 acc[4][2] = {};
  constexpr int NT = K / 64;

  // Prologue: stage tile 0 (units 0..3) into dbuf 0; wait units 0,1.
  stage_unit(0, 0, 0);
  stage_unit(1, 0, 0);
  stage_unit(2, 0, 0);
  stage_unit(3, 0, 0);
  WAIT_VMCNT(4);
  BARRIER();

  for (int t = 0; t < NT; ++t) {
    const int d = t & 1;
    const bool pre = (t + 1) < NT;
    const int kpre = (t + 1) * 64;

#pragma unroll
    for (int u = 0; u < 2; ++u) {   // unit = kk-half; 2 phases per K-tile
      f16x8 bfr[2][2], afr[4][2];
#pragma unroll
      for (int nt = 0; nt < 2; ++nt)
#pragma unroll
        for (int ks = 0; ks < 2; ++ks)
          bfr[nt][ks] = *(const f16x8*)(lds + boff(d, u, nt, ks));
#pragma unroll
      for (int mt = 0; mt < 4; ++mt)
#pragma unroll
        for (int ks = 0; ks < 2; ++ks)
          afr[mt][ks] = *(const f16x8*)(lds + aoff(d, u, mt, ks));
      if (pre) { stage_unit(2 * u, d ^ 1, kpre); stage_unit(2 * u + 1, d ^ 1, kpre); }
      BARRIER();
      __builtin_amdgcn_s_setprio(1);
#pragma unroll
      for (int ks = 0; ks < 2; ++ks)
#pragma unroll
        for (int mt = 0; mt < 4; ++mt)
#pragma unroll
          for (int nt = 0; nt < 2; ++nt)
            acc[mt][nt] = __builtin_amdgcn_mfma_f32_32x32x16_f16(
                afr[mt][ks], bfr[nt][ks], acc[mt][nt], 0, 0, 0);
      __builtin_amdgcn_s_setprio(0);
      if (u == 0) { if (pre) { WAIT_VMCNT(4); } else { WAIT_VMCNT(0); } }
      else        { if (pre) { WAIT_VMCNT(4); } }
      BARRIER();
    }
  }

  // Epilogue; C/D map: col=lane&31, row=(reg&3)+8*(reg>>2)+4*half [m74/m101]
  if constexpr (!FUSE) {
#pragma unroll
    for (int mt = 0; mt < 4; ++mt) {
#pragma unroll
      for (int nt = 0; nt < 2; ++nt) {
        const size_t gcol = col0 + wn + nt * 32 + l31;
        const float bia = bias[gcol];
        f16* Cp = C + (row0 + wm + mt * 32 + 4 * half) * (size_t)Nc + gcol;
#pragma unroll
        for (int reg = 0; reg < 16; ++reg) {
          const int ro = (reg & 3) + 8 * (reg >> 2);
          Cp[(size_t)ro * Nc] = (f16)fast_tanh(acc[mt][nt][reg] + bia);
        }
      }
    }
  } else {
    // Fused rowdot: lane covers col l31 of nt tiles; reduce over the 32-lane
    // half (shfl_xor 1..16 stays within the half), atomicAdd from l31==0.
#pragma unroll
    for (int mt = 0; mt < 4; ++mt) {
      float rsum[16];
#pragma unroll
      for (int reg = 0; reg < 16; ++reg) rsum[reg] = 0.f;
#pragma unroll
      for (int nt = 0; nt < 2; ++nt) {
        const size_t gcol = col0 + wn + nt * 32 + l31;
        const float bia = bias[gcol];
        const float* bp = batchf + (row0 + wm + mt * 32 + 4 * half) * DMODEL + gcol;
#pragma unroll
        for (int reg = 0; reg < 16; ++reg) {
          const int ro = (reg & 3) + 8 * (reg >> 2);
          rsum[reg] += fast_tanh(acc[mt][nt][reg] + bia) * bp[(size_t)ro * DMODEL];
        }
      }
#pragma unroll
      for (int reg = 0; reg < 16; ++reg) {
        float s = rsum[reg];
        s += __shfl_xor(s, 1, 64);
        s += __shfl_xor(s, 2, 64);
        s += __shfl_xor(s, 4, 64);
        s += __shfl_xor(s, 8, 64);
        s += __shfl_xor(s, 16, 64);
        if (l31 == 0) {
          const int ro = (reg & 3) + 8 * (reg >> 2);
          atomicAdd(&rowacc[row0 + wm + mt * 32 + 4 * half + ro], s);
        }
      }
    }
  }
}

// out[row] = sigmoid(rowacc[row])
__global__ void sigmoid_rows(const float* __restrict__ rowacc, float* __restrict__ out) {
  const int i = blockIdx.x * blockDim.x + threadIdx.x;
  out[i] = 1.0f / (1.0f + __expf(-rowacc[i]));
}

extern "C" void kernel_launch(void* const* d_in, const int* in_sizes, int n_in,
                              void* d_out, int out_size, void* d_ws, size_t ws_size,
                              hipStream_t stream) {
  const float* batch = (const float*)d_in[0];
  const float* W1    = (const float*)d_in[1];
  const float* b1    = (const float*)d_in[2];
  const float* W2    = (const float*)d_in[3];
  const float* b2    = (const float*)d_in[4];
  float* out = (float*)d_out;

  char* ws = (char*)d_ws;
  f16* batch_h  = (f16*)ws;   ws += (size_t)N_ROWS * DMODEL * sizeof(f16);  //  32 MB
  f16* W1_h     = (f16*)ws;   ws += (size_t)DFF * DMODEL * sizeof(f16);     //   8 MB
  f16* W2_h     = (f16*)ws;   ws += (size_t)DMODEL * DFF * sizeof(f16);     //   8 MB
  f16* inner_h  = (f16*)ws;   ws += (size_t)N_ROWS * DFF * sizeof(f16);     // 128 MB
  float* rowacc = (float*)ws; ws += (size_t)N_ROWS * sizeof(float);         //  64 KB

  static bool attr_set = false;
  if (!attr_set) {
    (void)hipFuncSetAttribute((const void*)gemm256_tanh<DMODEL, false>,
                              hipFuncAttributeMaxDynamicSharedMemorySize, 131072);
    (void)hipFuncSetAttribute((const void*)gemm256_tanh<DFF, true>,
                              hipFuncAttributeMaxDynamicSharedMemorySize, 131072);
    attr_set = true;
  }

  // merged casts + rowacc zero
  const size_t nb = (size_t)N_ROWS * DMODEL;
  const size_t nw = (size_t)DFF * DMODEL;
  const int total_thr = (int)((nb + 2 * nw) / 8 + N_ROWS / 8);
  cast_and_zero<<<total_thr / 256, 256, 0, stream>>>(batch, batch_h, W1, W1_h,
                                                     W2, W2_h, rowacc);

  dim3 g1(N_ROWS / 256, DFF / 256);     // (64, 16)
  gemm256_tanh<DMODEL, false><<<g1, 512, 131072, stream>>>(
      batch_h, W1_h, b1, inner_h, DFF, nullptr, nullptr);
  dim3 g2(N_ROWS / 256, DMODEL / 256);  // (64, 4)
  gemm256_tanh<DFF, true><<<g2, 512, 131072, stream>>>(
      inner_h, W2_h, b2, nullptr, DMODEL, rowacc, batch);

  sigmoid_rows<<<N_ROWS / 256, 256, 0, stream>>>(rowacc, out);
}